// Round 8
// baseline (295.363 us; speedup 1.0000x reference)
//
#include <hip/hip_runtime.h>

// AxialAttention3D — round 8: BK=16 + 4-phase attention => 29KB LDS => 5 blocks/CU (occupancy fix)
// B=2, C=512, D=32, H=32, W=32, heads=8, head_dim=64

typedef __bf16 bf16x8 __attribute__((ext_vector_type(8)));
typedef float  f32x4  __attribute__((ext_vector_type(4)));
typedef float  f32x16 __attribute__((ext_vector_type(16)));

__device__ __forceinline__ float b2f(unsigned int u) {
    union { float f; unsigned int i; } x; x.i = u << 16; return x.f;
}
__device__ __forceinline__ unsigned short f2b(float f) {
    union { float f; unsigned int i; } x; x.f = f;
    unsigned int r = x.i + 0x7FFFu + ((x.i >> 16) & 1u);
    return (unsigned short)(r >> 16);
}
__device__ __forceinline__ unsigned int cvtpk(float lo, float hi) {
    unsigned int r;
    asm("v_cvt_pk_bf16_f32 %0, %1, %2" : "=v"(r) : "v"(lo), "v"(hi));
    return r;
}
__device__ __forceinline__ f32x4 mfma16(bf16x8 a, bf16x8 b, f32x4 c) {
    return __builtin_amdgcn_mfma_f32_16x16x32_bf16(a, b, c, 0, 0, 0);
}
__device__ __forceinline__ f32x16 mfma32(bf16x8 a, bf16x8 b, f32x16 c) {
    return __builtin_amdgcn_mfma_f32_32x32x16_bf16(a, b, c, 0, 0, 0);
}
__device__ __forceinline__ void gload16(const void* g, void* l) {
    __builtin_amdgcn_global_load_lds((const unsigned int*)g, (unsigned int*)l, 16, 0, 0);
}

// ======================= xprep3: x -> xB k-major tiles (coalesced both sides) — unchanged =======================
__global__ __launch_bounds__(256) void xprep3(const float* __restrict__ x,
                                              const float* __restrict__ wq_f,
                                              const float* __restrict__ wo_f,
                                              unsigned short* __restrict__ xB,
                                              unsigned short* __restrict__ wT,
                                              unsigned short* __restrict__ wo_bf) {
    const int bid = blockIdx.x;
    const int tid = threadIdx.x;
    if (bid < 2048) {
        __shared__ __align__(16) char tile[32768];
        const int ck = bid & 7, dq = (bid >> 3) & 3, h = (bid >> 5) & 31, b = bid >> 10;

        const int cg = tid & 31;
        const int dl = tid >> 5;
        const int d  = dq * 8 + dl;
        const float* p0 = x + (size_t)b * 16777216 + (size_t)(ck * 64 + cg * 2) * 32768 + d * 1024 + h * 32;
        const float* p1 = p0 + 32768;
        const int cb = (cg * 4) ^ (dl << 4);
        #pragma unroll
        for (int k = 0; k < 8; ++k) {
            float4 a0 = *(const float4*)(p0 + 4 * k);
            float4 a1 = *(const float4*)(p1 + 4 * k);
            *(unsigned int*)(tile + dl * 4096 + (4 * k + 0) * 128 + cb) = cvtpk(a0.x, a1.x);
            *(unsigned int*)(tile + dl * 4096 + (4 * k + 1) * 128 + cb) = cvtpk(a0.y, a1.y);
            *(unsigned int*)(tile + dl * 4096 + (4 * k + 2) * 128 + cb) = cvtpk(a0.z, a1.z);
            *(unsigned int*)(tile + dl * 4096 + (4 * k + 3) * 128 + cb) = cvtpk(a0.w, a1.w);
        }
        __syncthreads();
        const int odl = tid & 7, ot = (tid >> 3) & 7, okb = tid >> 6;
        #pragma unroll
        for (int i = 0; i < 8; ++i) {
            const int wg = i >> 1, kkl = i & 1;
            const int cbyte = (kkl * 64 + okb * 16) ^ (odl << 4);
            uint4 v = *(const uint4*)(tile + odl * 4096 + (wg * 8 + ot) * 128 + cbyte);
            const int G  = (b * 32 + h) * 4 + wg;
            const int kk = ck * 2 + kkl;
            *(uint4*)(xB + (size_t)G * 131072 + kk * 8192 + okb * 2048 +
                      (ot * 32 + dq * 8 + odl) * 8) = v;
        }
    } else {
        const int gidx = (bid - 2048) * 256 + tid;
        if (gidx < 98304) {
            const int r  = gidx % 192;
            const int qd = gidx / 192;
            const int kb = qd & 3, kk = (qd >> 2) & 15, n = qd >> 6;
            const int R  = (r >> 6) * 512 + n * 64 + (r & 63);
            const float* s = wq_f + R * 512 + kk * 32 + kb * 8;
            float4 a0 = *(const float4*)s;
            float4 a1 = *(const float4*)(s + 4);
            *(uint4*)(wT + (size_t)gidx * 8) =
                make_uint4(cvtpk(a0.x, a0.y), cvtpk(a0.z, a0.w), cvtpk(a1.x, a1.y), cvtpk(a1.z, a1.w));
        } else {
            const int g2 = gidx - 98304;
            const float* s = wo_f + (size_t)g2 * 8;
            float4 a0 = *(const float4*)s;
            float4 a1 = *(const float4*)(s + 4);
            *(uint4*)(wo_bf + (size_t)g2 * 8) =
                make_uint4(cvtpk(a0.x, a0.y), cvtpk(a0.z, a0.w), cvtpk(a1.x, a1.y), cvtpk(a1.z, a1.w));
        }
    }
}

// ======================= fused QKV-GEMM + attention: 29KB LDS, 5 blocks/CU =======================
__global__ __launch_bounds__(256, 2)
void axial_ab3(const unsigned short* __restrict__ xB,
               const unsigned short* __restrict__ wT,
               const float* __restrict__ bq,
               unsigned short* __restrict__ ao)
{
    __shared__ __align__(16) char lds[29440];
    // staging: A 2 x [2 kb][192 r][16B] = 12KB @0; B 2 x [2 kb][256 r][16B] = 16KB @12288 (end 28672)
    // attn overlay (per 2-t phase): QT [2t][32 d][128B] @0; KT @8192; VT [64 e][128B] @16384;
    //                               P [2t][32 i][64B] @24576; bias 768B @28672
    const int SA0 = 0, SB0 = 12288;
    const int QT0 = 0, KT0 = 8192, VT0 = 16384, P0 = 24576, BIAS0 = 28672;
    float* bias_s = (float*)(lds + BIAS0);

    const int bid = blockIdx.x;
    const int vid = (bid & 7) * 256 + (bid >> 3);
    const int n   = vid & 7;
    const int G   = vid >> 3;
    const int b   = G >> 7, h = (G >> 2) & 31, wg = G & 3;
    const int sbase = b * 32768 + h * 32 + wg * 8;

    const int tid = threadIdx.x;
    const int wv  = tid >> 6;
    const int l   = tid & 63;
    const int l31 = l & 31;
    const int hh  = l >> 5;
    const int wm  = wv >> 1;
    const int wn  = wv & 1;

    const unsigned short* wA = wT + (size_t)n * 98304;   // [32 kk][2 kb][192 r][8]
    const unsigned short* xG = xB + (size_t)G * 131072;  // [32 kk][2 kb][256 r][8]

    auto stage = [&](int kk, int sl) {
        // A: 6 chunks of 1KB
        gload16(wA + kk * 3072 + wv * 512 + l * 8, lds + SA0 + sl * 6144 + wv * 1024);
        if (wv < 2)
            gload16(wA + kk * 3072 + (4 + wv) * 512 + l * 8,
                    lds + SA0 + sl * 6144 + (4 + wv) * 1024);
        // B: 8 chunks
        #pragma unroll
        for (int i = 0; i < 2; ++i) {
            const int j = wv * 2 + i;
            gload16(xG + kk * 4096 + j * 512 + l * 8, lds + SB0 + sl * 8192 + j * 1024);
        }
    };

    f32x16 acc[3][4];
    #pragma unroll
    for (int mf = 0; mf < 3; ++mf)
        #pragma unroll
        for (int nf = 0; nf < 4; ++nf) acc[mf][nf] = (f32x16)0.f;

    auto gphase = [&](int sl) {
        bf16x8 af[3], bfr[4];
        #pragma unroll
        for (int mf = 0; mf < 3; ++mf)
            af[mf] = *(const bf16x8*)(lds + SA0 + sl * 6144 + hh * 3072 +
                                      (wm * 96 + mf * 32 + l31) * 16);
        #pragma unroll
        for (int nf = 0; nf < 4; ++nf)
            bfr[nf] = *(const bf16x8*)(lds + SB0 + sl * 8192 + hh * 4096 +
                                       (wn * 128 + nf * 32 + l31) * 16);
        #pragma unroll
        for (int mf = 0; mf < 3; ++mf)
            #pragma unroll
            for (int nf = 0; nf < 4; ++nf)
                acc[mf][nf] = mfma32(af[mf], bfr[nf], acc[mf][nf]);
    };

    stage(0, 0);
    asm volatile("s_waitcnt vmcnt(0)" ::: "memory");
    __builtin_amdgcn_s_barrier();
    __builtin_amdgcn_sched_barrier(0);
    #pragma unroll
    for (int kk = 0; kk < 32; ++kk) {
        if (kk < 31) stage(kk + 1, (kk + 1) & 1);
        __builtin_amdgcn_s_setprio(1);
        gphase(kk & 1);
        __builtin_amdgcn_s_setprio(0);
        asm volatile("s_waitcnt vmcnt(0) lgkmcnt(0)" ::: "memory");
        __builtin_amdgcn_s_barrier();
        __builtin_amdgcn_sched_barrier(0);
    }

    if (tid < 192) bias_s[tid] = bq[(tid >> 6) * 512 + n * 64 + (tid & 63)];
    __syncthreads();

    // ---- attention in 4 phases of 2 t's; acc stays live ----
    #pragma unroll
    for (int p = 0; p < 4; ++p) {
        const int np0 = (p & 1) * 2;
        if (wn == (p >> 1)) {
            // scatter this phase's 2 t-columns of C into attention layouts
            #pragma unroll
            for (int mf = 0; mf < 3; ++mf) {
                const int m0 = wm * 96 + mf * 32;
                #pragma unroll
                for (int tl = 0; tl < 2; ++tl) {
                    const int nf = np0 + tl;
                    const int d  = l31;
                    const f32x16 v = acc[mf][nf];
                    if (m0 < 128) {
                        const int base = (m0 < 64) ? QT0 : KT0;
                        const int c0g  = (m0 & 63) >> 3;
                        #pragma unroll
                        for (int q8 = 0; q8 < 4; ++q8) {
                            float4 bb = *(const float4*)(bias_s + m0 + 8 * q8 + 4 * hh);
                            unsigned int u0 = cvtpk(v[4 * q8]     + bb.x, v[4 * q8 + 1] + bb.y);
                            unsigned int u1 = cvtpk(v[4 * q8 + 2] + bb.z, v[4 * q8 + 3] + bb.w);
                            *(uint2*)(lds + base + tl * 4096 + d * 128 +
                                      (((c0g + q8) ^ (d & 7)) << 4) + 8 * hh) = make_uint2(u0, u1);
                        }
                    } else {
                        const int e0 = m0 - 128;
                        const int jj = tl * 32 + l31;
                        #pragma unroll
                        for (int reg = 0; reg < 16; ++reg) {
                            const int e = e0 + (reg & 3) + 8 * (reg >> 2) + 4 * hh;
                            *(unsigned short*)(lds + VT0 + e * 128 +
                                               (((jj >> 3) ^ (e & 7)) << 4) + ((2 * jj) & 15)) =
                                f2b(v[reg]);
                        }
                    }
                }
            }
        }
        __syncthreads();

        // attn: wave -> (t_loc = wv&1, c-half cf = wv>>1); QK^T+softmax duplicated per cf pair
        {
            const int tl = wv & 1;
            const int cf = wv >> 1;
            const int qg = l >> 4;
            f32x4 sacc[2][2];
            sacc[0][0] = (f32x4)0.f; sacc[0][1] = (f32x4)0.f;
            sacc[1][0] = (f32x4)0.f; sacc[1][1] = (f32x4)0.f;
            #pragma unroll
            for (int kh = 0; kh < 2; ++kh) {
                bf16x8 qa[2], kb_[2];
                #pragma unroll
                for (int mt = 0; mt < 2; ++mt) {
                    const int i = mt * 16 + (l & 15);
                    qa[mt] = *(const bf16x8*)(lds + QT0 + tl * 4096 + i * 128 +
                                              (((kh * 4 + qg) ^ (i & 7)) << 4));
                }
                #pragma unroll
                for (int nt = 0; nt < 2; ++nt) {
                    const int jj = nt * 16 + (l & 15);
                    kb_[nt] = *(const bf16x8*)(lds + KT0 + tl * 4096 + jj * 128 +
                                               (((kh * 4 + qg) ^ (jj & 7)) << 4));
                }
                #pragma unroll
                for (int mt = 0; mt < 2; ++mt)
                    #pragma unroll
                    for (int nt = 0; nt < 2; ++nt)
                        sacc[mt][nt] = mfma16(qa[mt], kb_[nt], sacc[mt][nt]);
            }
            #pragma unroll
            for (int mt = 0; mt < 2; ++mt) {
                #pragma unroll
                for (int reg = 0; reg < 4; ++reg) {
                    float s0 = sacc[mt][0][reg] * 0.125f;
                    float s1 = sacc[mt][1][reg] * 0.125f;
                    float m = fmaxf(s0, s1);
                    m = fmaxf(m, __shfl_xor(m, 1));
                    m = fmaxf(m, __shfl_xor(m, 2));
                    m = fmaxf(m, __shfl_xor(m, 4));
                    m = fmaxf(m, __shfl_xor(m, 8));
                    float p0 = __expf(s0 - m);
                    float p1 = __expf(s1 - m);
                    float ss = p0 + p1;
                    ss += __shfl_xor(ss, 1);
                    ss += __shfl_xor(ss, 2);
                    ss += __shfl_xor(ss, 4);
                    ss += __shfl_xor(ss, 8);
                    float inv = 1.0f / ss;
                    const int i = mt * 16 + 4 * qg + reg;
                    #pragma unroll
                    for (int nt = 0; nt < 2; ++nt) {
                        const int j = nt * 16 + (l & 15);
                        *(unsigned short*)(lds + P0 + tl * 2048 + i * 64 +
                                           (((j >> 3) ^ (i & 3)) << 4) + ((2 * j) & 15)) =
                            f2b((nt ? p1 : p0) * inv);
                    }
                }
            }
            asm volatile("s_waitcnt lgkmcnt(0)" ::: "memory");
            __builtin_amdgcn_sched_barrier(0);

            // PV transposed: outT[c][i] = sum_j VT[c][jj] * P[i][j]; this wave: c in [cf*32, cf*32+32)
            f32x16 oa = (f32x16)0.f;
            #pragma unroll
            for (int ks = 0; ks < 2; ++ks) {
                bf16x8 pb = *(const bf16x8*)(lds + P0 + tl * 2048 + l31 * 64 +
                                             (((ks * 2 + hh) ^ (l31 & 3)) << 4));
                const int c = cf * 32 + l31;
                bf16x8 vv = *(const bf16x8*)(lds + VT0 + c * 128 +
                                             (((tl * 4 + ks * 2 + hh) ^ (c & 7)) << 4));
                oa = mfma32(vv, pb, oa);
            }
            const size_t srow = (size_t)(sbase + l31 * 1024 + p * 2 + tl) * 512 + n * 64;
            #pragma unroll
            for (int q8 = 0; q8 < 4; ++q8) {
                const int cb = cf * 32 + 8 * q8 + 4 * hh;
                float4 bb = *(const float4*)(bias_s + 128 + cb);
                unsigned int u0 = cvtpk(oa[4 * q8]     + bb.x, oa[4 * q8 + 1] + bb.y);
                unsigned int u1 = cvtpk(oa[4 * q8 + 2] + bb.z, oa[4 * q8 + 3] + bb.w);
                *(uint2*)(ao + srow + cb) = make_uint2(u0, u1);
            }
        }
        __syncthreads();
    }
}

// ======================= out-projection GEMM + bias + residual (unchanged) =======================
__global__ __launch_bounds__(256, 2)
void axial_out(const unsigned short* __restrict__ ao,
               const unsigned short* __restrict__ wo,
               const float* __restrict__ bo,
               const float* __restrict__ x,
               float* __restrict__ out)
{
    __shared__ __align__(16) char lds[65536];
    const int bid = blockIdx.x;
    const int vid = (bid & 7) * 256 + (bid >> 3);
    const int mt_ = vid & 3;
    const int nt_ = vid >> 2;
    const int m_base = mt_ * 128;
    const int s_base = nt_ * 128;
    const int bb  = s_base >> 15;
    const int spl = s_base & 32767;
    const float* xblk = x + (size_t)bb * 16777216 + spl;
    float* oblk = out + (size_t)bb * 16777216 + spl;

    const int tid = threadIdx.x;
    const int wv  = tid >> 6;
    const int l   = tid & 63;
    const int l31 = l & 31;
    const int hh  = l >> 5;
    const int wm  = wv >> 1;
    const int wn  = wv & 1;

    auto stage = [&](int kk, int buf) {
        #pragma unroll
        for (int i = 0; i < 4; ++i) {
            const int il  = wv * 4 + i;
            const int row = il * 8 + (l >> 3);
            const unsigned short* srcA = wo + (m_base + row) * 512 + kk * 64 +
                                         (((l & 7) ^ (row & 7)) << 3);
            gload16(srcA, lds + buf * 16384 + il * 1024);
            const unsigned short* srcB = ao + (size_t)(s_base + row) * 512 + kk * 64 +
                                         (((l & 7) ^ (row & 7)) << 3);
            gload16(srcB, lds + 32768 + buf * 16384 + il * 1024);
        }
    };

    f32x16 acc[2][2];
    acc[0][0] = (f32x16)0.f; acc[0][1] = (f32x16)0.f;
    acc[1][0] = (f32x16)0.f; acc[1][1] = (f32x16)0.f;

    stage(0, 0);
    __syncthreads();
    int cur = 0;
    for (int kk = 0; kk < 8; ++kk) {
        if (kk < 7) stage(kk + 1, cur ^ 1);
        #pragma unroll
        for (int ks = 0; ks < 4; ++ks) {
            bf16x8 af[2], bfr[2];
            #pragma unroll
            for (int mf = 0; mf < 2; ++mf) {
                const int row = wm * 64 + mf * 32 + l31;
                af[mf] = *(const bf16x8*)(lds + cur * 16384 + row * 128 +
                                          (((ks * 2 + hh) ^ (row & 7)) << 4));
            }
            #pragma unroll
            for (int nf = 0; nf < 2; ++nf) {
                const int row = wn * 64 + nf * 32 + l31;
                bfr[nf] = *(const bf16x8*)(lds + 32768 + cur * 16384 + row * 128 +
                                           (((ks * 2 + hh) ^ (row & 7)) << 4));
            }
            #pragma unroll
            for (int mf = 0; mf < 2; ++mf)
                #pragma unroll
                for (int nf = 0; nf < 2; ++nf)
                    acc[mf][nf] = mfma32(af[mf], bfr[nf], acc[mf][nf]);
        }
        __syncthreads();
        cur ^= 1;
    }

    #pragma unroll
    for (int mf = 0; mf < 2; ++mf) {
        #pragma unroll
        for (int reg = 0; reg < 16; ++reg) {
            const int co = m_base + wm * 64 + mf * 32 + (reg & 3) + 8 * (reg >> 2) + 4 * hh;
            const float bias = bo[co];
            #pragma unroll
            for (int nf = 0; nf < 2; ++nf) {
                const int sl = wn * 64 + nf * 32 + l31;
                oblk[(size_t)co * 32768 + sl] = acc[mf][nf][reg] + bias +
                                                xblk[(size_t)co * 32768 + sl];
            }
        }
    }
}

// ======================= fallback path (round-2 fused) =======================
__global__ __launch_bounds__(256) void wconvert(const float* __restrict__ wq,
                                                const float* __restrict__ wo,
                                                unsigned short* __restrict__ dst) {
    int i = blockIdx.x * 256 + threadIdx.x;
    const float* src;
    int off;
    if (i < 196608) { src = wq; off = i * 4; }
    else            { src = wo; off = (i - 196608) * 4; }
    float4 v = *(const float4*)(src + off);
    *(uint2*)(dst + (size_t)i * 4) = make_uint2(cvtpk(v.x, v.y), cvtpk(v.z, v.w));
}

__device__ __forceinline__ int adr_qk(int row, int cb) { return row * 2048 + (cb ^ ((row & 7) << 4)); }
__device__ __forceinline__ int adr_x (int row, int cb) { return 98304 + row * 1024 + (cb ^ ((row & 7) << 4)); }
__device__ __forceinline__ int adr_xl(int row, int cb) { return 131072 + row * 1024 + (cb ^ ((row & 7) << 4)); }
__device__ __forceinline__ int adr_v (int e, int jb)   { int a = e * 64 + jb; return 65536 + (a ^ ((e & 7) << 4)); }

__global__ __launch_bounds__(512, 1)
void axial3d_mfma(const float* __restrict__ x,
                  const float* __restrict__ bq,
                  const float* __restrict__ bo,
                  const unsigned short* __restrict__ wq,
                  const unsigned short* __restrict__ wo,
                  float* __restrict__ out) {
    __shared__ char lds[163840];
    const int bid  = blockIdx.x;
    const int work = (bid & 7) * 256 + (bid >> 3);
    const int b    = work >> 10;
    const int h    = (work >> 5) & 31;
    const int w    = work & 31;
    const float* xb = x   + ((size_t)b * 16777216u) + h * 32 + w;
    float*       ob = out + ((size_t)b * 16777216u) + h * 32 + w;
    const int tid  = threadIdx.x;
    const int wv   = tid >> 6;
    const int lane = tid & 63;
    const int g    = lane >> 4;
    const int q    = lane & 15;
    {
        const int d  = tid & 31;
        const int c0 = tid >> 5;
        #pragma unroll
        for (int it = 0; it < 32; ++it) {
            int c = c0 + it * 16;
            float xv = xb[c * 32768 + d * 1024];
            unsigned short hi = f2b(xv);
            unsigned short lo = f2b(xv - b2f(hi));
            *(unsigned short*)(lds + adr_x(d, c * 2))  = hi;
            *(unsigned short*)(lds + adr_xl(d, c * 2)) = lo;
        }
    }
    __syncthreads();
    for (int tp = 0; tp < 3; ++tp) {
        const int mt0 = wv * 12 + tp * 4;
        f32x4 acc[4][2];
        #pragma unroll
        for (int t = 0; t < 4; ++t) { acc[t][0] = (f32x4)0.f; acc[t][1] = (f32x4)0.f; }
        #pragma unroll
        for (int kk = 0; kk < 16; ++kk) {
            bf16x8 bfr[2];
            #pragma unroll
            for (int nt = 0; nt < 2; ++nt)
                bfr[nt] = *(const bf16x8*)(lds + adr_x(nt * 16 + q, kk * 64 + g * 16));
            #pragma unroll
            for (int t = 0; t < 4; ++t) {
                const int o = (mt0 + t) * 16 + q;
                bf16x8 a = *(const bf16x8*)((const char*)wq + o * 1024 + kk * 64 + g * 16);
                acc[t][0] = mfma16(a, bfr[0], acc[t][0]);
                acc[t][1] = mfma16(a, bfr[1], acc[t][1]);
            }
        }
        #pragma unroll
        for (int t = 0; t < 4; ++t) {
            const int mt    = mt0 + t;
            const int obase = mt * 16 + 4 * g;
            float bias[4];
            #pragma unroll
            for (int r = 0; r < 4; ++r) bias[r] = bq[obase + r];
            if (mt < 64) {
                #pragma unroll
                for (int nt = 0; nt < 2; ++nt) {
                    const int d = nt * 16 + q;
                    unsigned int lo = f2b(acc[t][nt][0] + bias[0]) |
                                      ((unsigned int)f2b(acc[t][nt][1] + bias[1]) << 16);
                    unsigned int hi = f2b(acc[t][nt][2] + bias[2]) |
                                      ((unsigned int)f2b(acc[t][nt][3] + bias[3]) << 16);
                    *(uint2*)(lds + adr_qk(d, obase * 2)) = make_uint2(lo, hi);
                }
            } else {
                #pragma unroll
                for (int nt = 0; nt < 2; ++nt) {
                    const int d = nt * 16 + q;
                    #pragma unroll
                    for (int r = 0; r < 4; ++r) {
                        const int e = obase + r - 1024;
                        *(unsigned short*)(lds + adr_v(e, d * 2)) = f2b(acc[t][nt][r] + bias[r]);
                    }
                }
            }
        }
    }
    __syncthreads();
    {
        const int n = wv;
        f32x4 s[2][2];
        s[0][0] = (f32x4)0.f; s[0][1] = (f32x4)0.f;
        s[1][0] = (f32x4)0.f; s[1][1] = (f32x4)0.f;
        #pragma unroll
        for (int kk = 0; kk < 2; ++kk) {
            bf16x8 a0 = *(const bf16x8*)(lds + adr_qk(q,      n * 128 + kk * 64 + g * 16));
            bf16x8 a1 = *(const bf16x8*)(lds + adr_qk(16 + q, n * 128 + kk * 64 + g * 16));
            bf16x8 b0 = *(const bf16x8*)(lds + adr_qk(q,      1024 + n * 128 + kk * 64 + g * 16));
            bf16x8 b1 = *(const bf16x8*)(lds + adr_qk(16 + q, 1024 + n * 128 + kk * 64 + g * 16));
            s[0][0] = mfma16(a0, b0, s[0][0]);
            s[0][1] = mfma16(a0, b1, s[0][1]);
            s[1][0] = mfma16(a1, b0, s[1][0]);
            s[1][1] = mfma16(a1, b1, s[1][1]);
        }
        float pv[2][2][4];
        #pragma unroll
        for (int it = 0; it < 2; ++it) {
            #pragma unroll
            for (int r = 0; r < 4; ++r) {
                float s0 = s[it][0][r] * 0.125f;
                float s1 = s[it][1][r] * 0.125f;
                float m = fmaxf(s0, s1);
                m = fmaxf(m, __shfl_xor(m, 1));
                m = fmaxf(m, __shfl_xor(m, 2));
                m = fmaxf(m, __shfl_xor(m, 4));
                m = fmaxf(m, __shfl_xor(m, 8));
                float p0 = __expf(s0 - m);
                float p1 = __expf(s1 - m);
                float ss = p0 + p1;
                ss += __shfl_xor(ss, 1);
                ss += __shfl_xor(ss, 2);
                ss += __shfl_xor(ss, 4);
                ss += __shfl_xor(ss, 8);
                float inv = 1.0f / ss;
                pv[it][0][r] = p0 * inv;
                pv[it][1][r] = p1 * inv;
            }
        }
        #pragma unroll
        for (int it = 0; it < 2; ++it)
            #pragma unroll
            for (int jt = 0; jt < 2; ++jt)
                #pragma unroll
                for (int r = 0; r < 4; ++r) {
                    const int i = it * 16 + 4 * g + r;
                    *(unsigned short*)(lds + adr_qk(i, n * 128 + (jt * 16 + q) * 2)) =
                        f2b(pv[it][jt][r]);
                }
        asm volatile("s_waitcnt lgkmcnt(0)" ::: "memory");
        __builtin_amdgcn_sched_barrier(0);
        bf16x8 pa0 = *(const bf16x8*)(lds + adr_qk(q,      n * 128 + g * 16));
        bf16x8 pa1 = *(const bf16x8*)(lds + adr_qk(16 + q, n * 128 + g * 16));
        #pragma unroll
        for (int et = 0; et < 4; ++et) {
            const int e = n * 64 + et * 16 + q;
            bf16x8 vb = *(const bf16x8*)(lds + adr_v(e, g * 16));
            f32x4 o0 = mfma16(pa0, vb, (f32x4)0.f);
            f32x4 o1 = mfma16(pa1, vb, (f32x4)0.f);
            const int cb = 1024 + n * 128 + (et * 16 + q) * 2;
            #pragma unroll
            for (int r = 0; r < 4; ++r) {
                *(unsigned short*)(lds + adr_qk(4 * g + r, cb))      = f2b(o0[r]);
                *(unsigned short*)(lds + adr_qk(16 + 4 * g + r, cb)) = f2b(o1[r]);
            }
        }
    }
    __syncthreads();
    for (int p4 = 0; p4 < 4; ++p4) {
        const int mt = wv * 4 + p4;
        f32x4 acc[2];
        acc[0] = (f32x4)0.f; acc[1] = (f32x4)0.f;
        #pragma unroll
        for (int kk = 0; kk < 16; ++kk) {
            bf16x8 b0 = *(const bf16x8*)(lds + adr_qk(q,      1024 + kk * 64 + g * 16));
            bf16x8 b1 = *(const bf16x8*)(lds + adr_qk(16 + q, 1024 + kk * 64 + g * 16));
            bf16x8 a  = *(const bf16x8*)((const char*)wo + (mt * 16 + q) * 1024 + kk * 64 + g * 16);
            acc[0] = mfma16(a, b0, acc[0]);
            acc[1] = mfma16(a, b1, acc[1]);
        }
        const int obase = mt * 16 + 4 * g;
        float bias[4];
        #pragma unroll
        for (int r = 0; r < 4; ++r) bias[r] = bo[obase + r];
        #pragma unroll
        for (int nt = 0; nt < 2; ++nt) {
            const int d = nt * 16 + q;
            uint2 xh = *(const uint2*)(lds + adr_x(d, obase * 2));
            uint2 xl = *(const uint2*)(lds + adr_xl(d, obase * 2));
            float res[4];
            res[0] = b2f(xh.x & 0xffffu) + b2f(xl.x & 0xffffu);
            res[1] = b2f(xh.x >> 16)     + b2f(xl.x >> 16);
            res[2] = b2f(xh.y & 0xffffu) + b2f(xl.y & 0xffffu);
            res[3] = b2f(xh.y >> 16)     + b2f(xl.y >> 16);
            #pragma unroll
            for (int r = 0; r < 4; ++r)
                ob[(obase + r) * 32768 + d * 1024] = acc[nt][r] + bias[r] + res[r];
        }
    }
}

// ======================= launch =======================
extern "C" void kernel_launch(void* const* d_in, const int* in_sizes, int n_in,
                              void* d_out, int out_size, void* d_ws, size_t ws_size,
                              hipStream_t stream) {
    const float* x     = (const float*)d_in[0];
    const float* w_qkv = (const float*)d_in[1];
    const float* b_qkv = (const float*)d_in[2];
    const float* w_out = (const float*)d_in[3];
    const float* b_out = (const float*)d_in[4];
    float* out = (float*)d_out;

    const size_t XB_OFF = 0;                 // 64 MB k-major tiles
    const size_t AO_OFF = 67108864;          // 64 MB bf16 [65536][512]
    const size_t WT_OFF = 134217728;         // 1.5 MB wT + 0.5 MB wo_bf
    const size_t NEED   = 136314880;

    if (ws_size >= NEED) {
        unsigned short* xB    = (unsigned short*)((char*)d_ws + XB_OFF);
        unsigned short* ao    = (unsigned short*)((char*)d_ws + AO_OFF);
        unsigned short* wTt   = (unsigned short*)((char*)d_ws + WT_OFF);
        unsigned short* wo_bf = wTt + 786432;
        xprep3   <<<dim3(2560), dim3(256), 0, stream>>>(x, w_qkv, w_out, xB, wTt, wo_bf);
        axial_ab3<<<dim3(2048), dim3(256), 0, stream>>>(xB, wTt, b_qkv, ao);
        axial_out<<<dim3(2048), dim3(256), 0, stream>>>(ao, wo_bf, b_out, x, out);
    } else {
        unsigned short* wbf = (unsigned short*)d_ws;
        wconvert<<<dim3(1024), dim3(256), 0, stream>>>(w_qkv, w_out, wbf);
        axial3d_mfma<<<dim3(2048), dim3(512), 0, stream>>>(x, b_qkv, b_out,
                                                           wbf, wbf + 786432, out);
    }
}

// Round 9
// 272.538 us; speedup vs baseline: 1.0838x; 1.0838x over previous
//
#include <hip/hip_runtime.h>

// AxialAttention3D — round 9: R7 conflict-free layout + counted-vmcnt prefetch (A depth-1, B depth-2)
// B=2, C=512, D=32, H=32, W=32, heads=8, head_dim=64

typedef __bf16 bf16x8 __attribute__((ext_vector_type(8)));
typedef float  f32x4  __attribute__((ext_vector_type(4)));
typedef float  f32x16 __attribute__((ext_vector_type(16)));

__device__ __forceinline__ float b2f(unsigned int u) {
    union { float f; unsigned int i; } x; x.i = u << 16; return x.f;
}
__device__ __forceinline__ unsigned short f2b(float f) {
    union { float f; unsigned int i; } x; x.f = f;
    unsigned int r = x.i + 0x7FFFu + ((x.i >> 16) & 1u);
    return (unsigned short)(r >> 16);
}
__device__ __forceinline__ unsigned int cvtpk(float lo, float hi) {
    unsigned int r;
    asm("v_cvt_pk_bf16_f32 %0, %1, %2" : "=v"(r) : "v"(lo), "v"(hi));
    return r;
}
__device__ __forceinline__ f32x4 mfma16(bf16x8 a, bf16x8 b, f32x4 c) {
    return __builtin_amdgcn_mfma_f32_16x16x32_bf16(a, b, c, 0, 0, 0);
}
__device__ __forceinline__ f32x16 mfma32(bf16x8 a, bf16x8 b, f32x16 c) {
    return __builtin_amdgcn_mfma_f32_32x32x16_bf16(a, b, c, 0, 0, 0);
}
__device__ __forceinline__ void gload16(const void* g, void* l) {
    __builtin_amdgcn_global_load_lds((const unsigned int*)g, (unsigned int*)l, 16, 0, 0);
}

// ======================= xprep3: x -> xB k-major tiles (coalesced both sides) — unchanged =======================
__global__ __launch_bounds__(256) void xprep3(const float* __restrict__ x,
                                              const float* __restrict__ wq_f,
                                              const float* __restrict__ wo_f,
                                              unsigned short* __restrict__ xB,
                                              unsigned short* __restrict__ wT,
                                              unsigned short* __restrict__ wo_bf) {
    const int bid = blockIdx.x;
    const int tid = threadIdx.x;
    if (bid < 2048) {
        __shared__ __align__(16) char tile[32768];
        const int ck = bid & 7, dq = (bid >> 3) & 3, h = (bid >> 5) & 31, b = bid >> 10;

        const int cg = tid & 31;
        const int dl = tid >> 5;
        const int d  = dq * 8 + dl;
        const float* p0 = x + (size_t)b * 16777216 + (size_t)(ck * 64 + cg * 2) * 32768 + d * 1024 + h * 32;
        const float* p1 = p0 + 32768;
        const int cb = (cg * 4) ^ (dl << 4);
        #pragma unroll
        for (int k = 0; k < 8; ++k) {
            float4 a0 = *(const float4*)(p0 + 4 * k);
            float4 a1 = *(const float4*)(p1 + 4 * k);
            *(unsigned int*)(tile + dl * 4096 + (4 * k + 0) * 128 + cb) = cvtpk(a0.x, a1.x);
            *(unsigned int*)(tile + dl * 4096 + (4 * k + 1) * 128 + cb) = cvtpk(a0.y, a1.y);
            *(unsigned int*)(tile + dl * 4096 + (4 * k + 2) * 128 + cb) = cvtpk(a0.z, a1.z);
            *(unsigned int*)(tile + dl * 4096 + (4 * k + 3) * 128 + cb) = cvtpk(a0.w, a1.w);
        }
        __syncthreads();
        const int odl = tid & 7, ot = (tid >> 3) & 7, okb = tid >> 6;
        #pragma unroll
        for (int i = 0; i < 8; ++i) {
            const int wg = i >> 1, kkl = i & 1;
            const int cbyte = (kkl * 64 + okb * 16) ^ (odl << 4);
            uint4 v = *(const uint4*)(tile + odl * 4096 + (wg * 8 + ot) * 128 + cbyte);
            const int G  = (b * 32 + h) * 4 + wg;
            const int kk = ck * 2 + kkl;
            *(uint4*)(xB + (size_t)G * 131072 + kk * 8192 + okb * 2048 +
                      (ot * 32 + dq * 8 + odl) * 8) = v;
        }
    } else {
        const int gidx = (bid - 2048) * 256 + tid;
        if (gidx < 98304) {
            const int r  = gidx % 192;
            const int qd = gidx / 192;
            const int kb = qd & 3, kk = (qd >> 2) & 15, n = qd >> 6;
            const int R  = (r >> 6) * 512 + n * 64 + (r & 63);
            const float* s = wq_f + R * 512 + kk * 32 + kb * 8;
            float4 a0 = *(const float4*)s;
            float4 a1 = *(const float4*)(s + 4);
            *(uint4*)(wT + (size_t)gidx * 8) =
                make_uint4(cvtpk(a0.x, a0.y), cvtpk(a0.z, a0.w), cvtpk(a1.x, a1.y), cvtpk(a1.z, a1.w));
        } else {
            const int g2 = gidx - 98304;
            const float* s = wo_f + (size_t)g2 * 8;
            float4 a0 = *(const float4*)s;
            float4 a1 = *(const float4*)(s + 4);
            *(uint4*)(wo_bf + (size_t)g2 * 8) =
                make_uint4(cvtpk(a0.x, a0.y), cvtpk(a0.z, a0.w), cvtpk(a1.x, a1.y), cvtpk(a1.z, a1.w));
        }
    }
}

// ======================= fused QKV-GEMM + attention: counted-vmcnt pipeline =======================
__global__ __launch_bounds__(256, 2)
void axial_ab4(const unsigned short* __restrict__ xB,
               const unsigned short* __restrict__ wT,
               const float* __restrict__ bq,
               unsigned short* __restrict__ ao)
{
    __shared__ __align__(16) char lds[74496];
    // staging: A 2 slots x [4 kb][192 r][16B] = 12KB @0; B 3 slots x [4 kb][256 r][16B] = 16KB @24576
    // attn overlay (post-GEMM): QT [4t][32 d][128B] @0; KT @16384; VT [64 e][256B] @32768;
    //                           P [4t][32 i][64B] @49152; bias 768B @73728
    const int SA0 = 0, SB0 = 24576;
    const int QT0 = 0, KT0 = 16384, VT0 = 32768, P0 = 49152, BIAS0 = 73728;
    float* bias_s = (float*)(lds + BIAS0);

    const int bid = blockIdx.x;
    const int vid = (bid & 7) * 256 + (bid >> 3);
    const int n   = vid & 7;
    const int G   = vid >> 3;
    const int b   = G >> 7, h = (G >> 2) & 31, wg = G & 3;
    const int sbase = b * 32768 + h * 32 + wg * 8;

    const int tid = threadIdx.x;
    const int wv  = tid >> 6;
    const int l   = tid & 63;
    const int l31 = l & 31;
    const int hh  = l >> 5;
    const int wm  = wv >> 1;
    const int wn  = wv & 1;

    const unsigned short* wA = wT + (size_t)n * 98304;   // [16 kk][4 kb][192 r][8]
    const unsigned short* xG = xB + (size_t)G * 131072;  // [16 kk][4 kb][256 r][8]

    auto stageA = [&](int kk, int sl) {      // 3 gload16/wave (L2-hot weights)
        #pragma unroll
        for (int i = 0; i < 3; ++i) {
            const int j = wv * 3 + i;
            gload16(wA + kk * 6144 + j * 512 + l * 8, lds + SA0 + sl * 12288 + j * 1024);
        }
    };
    auto stageB = [&](int kk, int sl) {      // 4 gload16/wave (HBM-streamed xB)
        #pragma unroll
        for (int i = 0; i < 4; ++i) {
            const int j = wv * 4 + i;
            gload16(xG + kk * 8192 + j * 512 + l * 8, lds + SB0 + sl * 16384 + j * 1024);
        }
    };

    f32x16 acc[3][4];
    #pragma unroll
    for (int mf = 0; mf < 3; ++mf)
        #pragma unroll
        for (int nf = 0; nf < 4; ++nf) acc[mf][nf] = (f32x16)0.f;

    auto gphase = [&](int sa, int sb) {
        #pragma unroll
        for (int ks = 0; ks < 2; ++ks) {
            const int kb = ks * 2 + hh;
            bf16x8 af[3], bfr[4];
            #pragma unroll
            for (int mf = 0; mf < 3; ++mf)
                af[mf] = *(const bf16x8*)(lds + SA0 + sa * 12288 + kb * 3072 +
                                          (wm * 96 + mf * 32 + l31) * 16);
            #pragma unroll
            for (int nf = 0; nf < 4; ++nf)
                bfr[nf] = *(const bf16x8*)(lds + SB0 + sb * 16384 + kb * 4096 +
                                           (wn * 128 + nf * 32 + l31) * 16);
            #pragma unroll
            for (int mf = 0; mf < 3; ++mf)
                #pragma unroll
                for (int nf = 0; nf < 4; ++nf)
                    acc[mf][nf] = mfma32(af[mf], bfr[nf], acc[mf][nf]);
        }
    };

    // prologue: A0, B0, B1 in flight (queue order: A0(3), B0(4), B1(4))
    stageA(0, 0); stageB(0, 0); stageB(1, 1);
    asm volatile("s_waitcnt vmcnt(4)" ::: "memory");   // A0+B0 landed, B1 outstanding
    __builtin_amdgcn_s_barrier();
    __builtin_amdgcn_sched_barrier(0);

    #pragma unroll
    for (int kk = 0; kk < 16; ++kk) {
        if (kk < 15) stageA(kk + 1, (kk + 1) & 1);
        if (kk < 14) stageB(kk + 2, (kk + 2) % 3);
        __builtin_amdgcn_s_setprio(1);
        gphase(kk & 1, kk % 3);
        __builtin_amdgcn_s_setprio(0);
        asm volatile("s_waitcnt lgkmcnt(0)" ::: "memory");   // frag reads done before slot overwrite
        if (kk < 14)       { asm volatile("s_waitcnt vmcnt(4)" ::: "memory"); }  // A(kk+1)+B(kk+1) landed
        else if (kk == 14) { asm volatile("s_waitcnt vmcnt(0)" ::: "memory"); }
        __builtin_amdgcn_s_barrier();
        __builtin_amdgcn_sched_barrier(0);
    }

    if (tid < 192) bias_s[tid] = bq[(tid >> 6) * 512 + n * 64 + (tid & 63)];
    __syncthreads();

    // ---- attention in two halves of 4 t's each; acc stays live (as R7) ----
    #pragma unroll
    for (int ph = 0; ph < 2; ++ph) {
        if (wn == ph) {
            #pragma unroll
            for (int mf = 0; mf < 3; ++mf) {
                const int m0 = wm * 96 + mf * 32;
                #pragma unroll
                for (int nf = 0; nf < 4; ++nf) {
                    const int tl = nf;
                    const int d  = l31;
                    const f32x16 v = acc[mf][nf];
                    if (m0 < 128) {
                        const int base = (m0 < 64) ? QT0 : KT0;
                        const int c0g  = (m0 & 63) >> 3;
                        #pragma unroll
                        for (int p = 0; p < 4; ++p) {
                            float4 bb = *(const float4*)(bias_s + m0 + 8 * p + 4 * hh);
                            unsigned int u0 = cvtpk(v[4 * p]     + bb.x, v[4 * p + 1] + bb.y);
                            unsigned int u1 = cvtpk(v[4 * p + 2] + bb.z, v[4 * p + 3] + bb.w);
                            *(uint2*)(lds + base + tl * 4096 + d * 128 +
                                      (((c0g + p) ^ (d & 7)) << 4) + 8 * hh) = make_uint2(u0, u1);
                        }
                    } else {
                        const int e0 = m0 - 128;
                        const int jj = tl * 32 + l31;
                        #pragma unroll
                        for (int reg = 0; reg < 16; ++reg) {
                            const int e = e0 + (reg & 3) + 8 * (reg >> 2) + 4 * hh;
                            *(unsigned short*)(lds + VT0 + e * 256 +
                                               (((jj >> 3) ^ (e & 7)) << 4) + ((2 * jj) & 15)) =
                                f2b(v[reg]);
                        }
                    }
                }
            }
        }
        __syncthreads();

        {
            const int t  = wv;
            const int qg = l >> 4;
            f32x4 sacc[2][2];
            sacc[0][0] = (f32x4)0.f; sacc[0][1] = (f32x4)0.f;
            sacc[1][0] = (f32x4)0.f; sacc[1][1] = (f32x4)0.f;
            #pragma unroll
            for (int kh = 0; kh < 2; ++kh) {
                bf16x8 qa[2], kb_[2];
                #pragma unroll
                for (int mt = 0; mt < 2; ++mt) {
                    const int i = mt * 16 + (l & 15);
                    qa[mt] = *(const bf16x8*)(lds + QT0 + t * 4096 + i * 128 +
                                              (((kh * 4 + qg) ^ (i & 7)) << 4));
                }
                #pragma unroll
                for (int nt = 0; nt < 2; ++nt) {
                    const int jj = nt * 16 + (l & 15);
                    kb_[nt] = *(const bf16x8*)(lds + KT0 + t * 4096 + jj * 128 +
                                               (((kh * 4 + qg) ^ (jj & 7)) << 4));
                }
                #pragma unroll
                for (int mt = 0; mt < 2; ++mt)
                    #pragma unroll
                    for (int nt = 0; nt < 2; ++nt)
                        sacc[mt][nt] = mfma16(qa[mt], kb_[nt], sacc[mt][nt]);
            }
            #pragma unroll
            for (int mt = 0; mt < 2; ++mt) {
                #pragma unroll
                for (int reg = 0; reg < 4; ++reg) {
                    float s0 = sacc[mt][0][reg] * 0.125f;
                    float s1 = sacc[mt][1][reg] * 0.125f;
                    float m = fmaxf(s0, s1);
                    m = fmaxf(m, __shfl_xor(m, 1));
                    m = fmaxf(m, __shfl_xor(m, 2));
                    m = fmaxf(m, __shfl_xor(m, 4));
                    m = fmaxf(m, __shfl_xor(m, 8));
                    float p0 = __expf(s0 - m);
                    float p1 = __expf(s1 - m);
                    float ss = p0 + p1;
                    ss += __shfl_xor(ss, 1);
                    ss += __shfl_xor(ss, 2);
                    ss += __shfl_xor(ss, 4);
                    ss += __shfl_xor(ss, 8);
                    float inv = 1.0f / ss;
                    const int i = mt * 16 + 4 * qg + reg;
                    #pragma unroll
                    for (int nt = 0; nt < 2; ++nt) {
                        const int j = nt * 16 + (l & 15);
                        *(unsigned short*)(lds + P0 + t * 2048 + i * 64 +
                                           (((j >> 3) ^ (i & 3)) << 4) + ((2 * j) & 15)) =
                            f2b((nt ? p1 : p0) * inv);
                    }
                }
            }
            asm volatile("s_waitcnt lgkmcnt(0)" ::: "memory");
            __builtin_amdgcn_sched_barrier(0);

            f32x16 oa[2];
            oa[0] = (f32x16)0.f; oa[1] = (f32x16)0.f;
            #pragma unroll
            for (int ks = 0; ks < 2; ++ks) {
                bf16x8 pb = *(const bf16x8*)(lds + P0 + t * 2048 + l31 * 64 +
                                             (((ks * 2 + hh) ^ (l31 & 3)) << 4));
                #pragma unroll
                for (int cf = 0; cf < 2; ++cf) {
                    const int c = cf * 32 + l31;
                    bf16x8 vv = *(const bf16x8*)(lds + VT0 + c * 256 +
                                                 (((t * 4 + ks * 2 + hh) ^ (c & 7)) << 4));
                    oa[cf] = mfma32(vv, pb, oa[cf]);
                }
            }
            const size_t srow = (size_t)(sbase + l31 * 1024 + ph * 4 + t) * 512 + n * 64;
            #pragma unroll
            for (int cf = 0; cf < 2; ++cf) {
                #pragma unroll
                for (int p = 0; p < 4; ++p) {
                    const int cb = cf * 32 + 8 * p + 4 * hh;
                    float4 bb = *(const float4*)(bias_s + 128 + cb);
                    unsigned int u0 = cvtpk(oa[cf][4 * p]     + bb.x, oa[cf][4 * p + 1] + bb.y);
                    unsigned int u1 = cvtpk(oa[cf][4 * p + 2] + bb.z, oa[cf][4 * p + 3] + bb.w);
                    *(uint2*)(ao + srow + cb) = make_uint2(u0, u1);
                }
            }
        }
        __syncthreads();
    }
}

// ======================= out-projection GEMM + bias + residual (unchanged) =======================
__global__ __launch_bounds__(256, 2)
void axial_out(const unsigned short* __restrict__ ao,
               const unsigned short* __restrict__ wo,
               const float* __restrict__ bo,
               const float* __restrict__ x,
               float* __restrict__ out)
{
    __shared__ __align__(16) char lds[65536];
    const int bid = blockIdx.x;
    const int vid = (bid & 7) * 256 + (bid >> 3);
    const int mt_ = vid & 3;
    const int nt_ = vid >> 2;
    const int m_base = mt_ * 128;
    const int s_base = nt_ * 128;
    const int bb  = s_base >> 15;
    const int spl = s_base & 32767;
    const float* xblk = x + (size_t)bb * 16777216 + spl;
    float* oblk = out + (size_t)bb * 16777216 + spl;

    const int tid = threadIdx.x;
    const int wv  = tid >> 6;
    const int l   = tid & 63;
    const int l31 = l & 31;
    const int hh  = l >> 5;
    const int wm  = wv >> 1;
    const int wn  = wv & 1;

    auto stage = [&](int kk, int buf) {
        #pragma unroll
        for (int i = 0; i < 4; ++i) {
            const int il  = wv * 4 + i;
            const int row = il * 8 + (l >> 3);
            const unsigned short* srcA = wo + (m_base + row) * 512 + kk * 64 +
                                         (((l & 7) ^ (row & 7)) << 3);
            gload16(srcA, lds + buf * 16384 + il * 1024);
            const unsigned short* srcB = ao + (size_t)(s_base + row) * 512 + kk * 64 +
                                         (((l & 7) ^ (row & 7)) << 3);
            gload16(srcB, lds + 32768 + buf * 16384 + il * 1024);
        }
    };

    f32x16 acc[2][2];
    acc[0][0] = (f32x16)0.f; acc[0][1] = (f32x16)0.f;
    acc[1][0] = (f32x16)0.f; acc[1][1] = (f32x16)0.f;

    stage(0, 0);
    __syncthreads();
    int cur = 0;
    for (int kk = 0; kk < 8; ++kk) {
        if (kk < 7) stage(kk + 1, cur ^ 1);
        #pragma unroll
        for (int ks = 0; ks < 4; ++ks) {
            bf16x8 af[2], bfr[2];
            #pragma unroll
            for (int mf = 0; mf < 2; ++mf) {
                const int row = wm * 64 + mf * 32 + l31;
                af[mf] = *(const bf16x8*)(lds + cur * 16384 + row * 128 +
                                          (((ks * 2 + hh) ^ (row & 7)) << 4));
            }
            #pragma unroll
            for (int nf = 0; nf < 2; ++nf) {
                const int row = wn * 64 + nf * 32 + l31;
                bfr[nf] = *(const bf16x8*)(lds + 32768 + cur * 16384 + row * 128 +
                                           (((ks * 2 + hh) ^ (row & 7)) << 4));
            }
            #pragma unroll
            for (int mf = 0; mf < 2; ++mf)
                #pragma unroll
                for (int nf = 0; nf < 2; ++nf)
                    acc[mf][nf] = mfma32(af[mf], bfr[nf], acc[mf][nf]);
        }
        __syncthreads();
        cur ^= 1;
    }

    #pragma unroll
    for (int mf = 0; mf < 2; ++mf) {
        #pragma unroll
        for (int reg = 0; reg < 16; ++reg) {
            const int co = m_base + wm * 64 + mf * 32 + (reg & 3) + 8 * (reg >> 2) + 4 * hh;
            const float bias = bo[co];
            #pragma unroll
            for (int nf = 0; nf < 2; ++nf) {
                const int sl = wn * 64 + nf * 32 + l31;
                oblk[(size_t)co * 32768 + sl] = acc[mf][nf][reg] + bias +
                                                xblk[(size_t)co * 32768 + sl];
            }
        }
    }
}

// ======================= fallback path (round-2 fused) =======================
__global__ __launch_bounds__(256) void wconvert(const float* __restrict__ wq,
                                                const float* __restrict__ wo,
                                                unsigned short* __restrict__ dst) {
    int i = blockIdx.x * 256 + threadIdx.x;
    const float* src;
    int off;
    if (i < 196608) { src = wq; off = i * 4; }
    else            { src = wo; off = (i - 196608) * 4; }
    float4 v = *(const float4*)(src + off);
    *(uint2*)(dst + (size_t)i * 4) = make_uint2(cvtpk(v.x, v.y), cvtpk(v.z, v.w));
}

__device__ __forceinline__ int adr_qk(int row, int cb) { return row * 2048 + (cb ^ ((row & 7) << 4)); }
__device__ __forceinline__ int adr_x (int row, int cb) { return 98304 + row * 1024 + (cb ^ ((row & 7) << 4)); }
__device__ __forceinline__ int adr_xl(int row, int cb) { return 131072 + row * 1024 + (cb ^ ((row & 7) << 4)); }
__device__ __forceinline__ int adr_v (int e, int jb)   { int a = e * 64 + jb; return 65536 + (a ^ ((e & 7) << 4)); }

__global__ __launch_bounds__(512, 1)
void axial3d_mfma(const float* __restrict__ x,
                  const float* __restrict__ bq,
                  const float* __restrict__ bo,
                  const unsigned short* __restrict__ wq,
                  const unsigned short* __restrict__ wo,
                  float* __restrict__ out) {
    __shared__ char lds[163840];
    const int bid  = blockIdx.x;
    const int work = (bid & 7) * 256 + (bid >> 3);
    const int b    = work >> 10;
    const int h    = (work >> 5) & 31;
    const int w    = work & 31;
    const float* xb = x   + ((size_t)b * 16777216u) + h * 32 + w;
    float*       ob = out + ((size_t)b * 16777216u) + h * 32 + w;
    const int tid  = threadIdx.x;
    const int wv   = tid >> 6;
    const int lane = tid & 63;
    const int g    = lane >> 4;
    const int q    = lane & 15;
    {
        const int d  = tid & 31;
        const int c0 = tid >> 5;
        #pragma unroll
        for (int it = 0; it < 32; ++it) {
            int c = c0 + it * 16;
            float xv = xb[c * 32768 + d * 1024];
            unsigned short hi = f2b(xv);
            unsigned short lo = f2b(xv - b2f(hi));
            *(unsigned short*)(lds + adr_x(d, c * 2))  = hi;
            *(unsigned short*)(lds + adr_xl(d, c * 2)) = lo;
        }
    }
    __syncthreads();
    for (int tp = 0; tp < 3; ++tp) {
        const int mt0 = wv * 12 + tp * 4;
        f32x4 acc[4][2];
        #pragma unroll
        for (int t = 0; t < 4; ++t) { acc[t][0] = (f32x4)0.f; acc[t][1] = (f32x4)0.f; }
        #pragma unroll
        for (int kk = 0; kk < 16; ++kk) {
            bf16x8 bfr[2];
            #pragma unroll
            for (int nt = 0; nt < 2; ++nt)
                bfr[nt] = *(const bf16x8*)(lds + adr_x(nt * 16 + q, kk * 64 + g * 16));
            #pragma unroll
            for (int t = 0; t < 4; ++t) {
                const int o = (mt0 + t) * 16 + q;
                bf16x8 a = *(const bf16x8*)((const char*)wq + o * 1024 + kk * 64 + g * 16);
                acc[t][0] = mfma16(a, bfr[0], acc[t][0]);
                acc[t][1] = mfma16(a, bfr[1], acc[t][1]);
            }
        }
        #pragma unroll
        for (int t = 0; t < 4; ++t) {
            const int mt    = mt0 + t;
            const int obase = mt * 16 + 4 * g;
            float bias[4];
            #pragma unroll
            for (int r = 0; r < 4; ++r) bias[r] = bq[obase + r];
            if (mt < 64) {
                #pragma unroll
                for (int nt = 0; nt < 2; ++nt) {
                    const int d = nt * 16 + q;
                    unsigned int lo = f2b(acc[t][nt][0] + bias[0]) |
                                      ((unsigned int)f2b(acc[t][nt][1] + bias[1]) << 16);
                    unsigned int hi = f2b(acc[t][nt][2] + bias[2]) |
                                      ((unsigned int)f2b(acc[t][nt][3] + bias[3]) << 16);
                    *(uint2*)(lds + adr_qk(d, obase * 2)) = make_uint2(lo, hi);
                }
            } else {
                #pragma unroll
                for (int nt = 0; nt < 2; ++nt) {
                    const int d = nt * 16 + q;
                    #pragma unroll
                    for (int r = 0; r < 4; ++r) {
                        const int e = obase + r - 1024;
                        *(unsigned short*)(lds + adr_v(e, d * 2)) = f2b(acc[t][nt][r] + bias[r]);
                    }
                }
            }
        }
    }
    __syncthreads();
    {
        const int n = wv;
        f32x4 s[2][2];
        s[0][0] = (f32x4)0.f; s[0][1] = (f32x4)0.f;
        s[1][0] = (f32x4)0.f; s[1][1] = (f32x4)0.f;
        #pragma unroll
        for (int kk = 0; kk < 2; ++kk) {
            bf16x8 a0 = *(const bf16x8*)(lds + adr_qk(q,      n * 128 + kk * 64 + g * 16));
            bf16x8 a1 = *(const bf16x8*)(lds + adr_qk(16 + q, n * 128 + kk * 64 + g * 16));
            bf16x8 b0 = *(const bf16x8*)(lds + adr_qk(q,      1024 + n * 128 + kk * 64 + g * 16));
            bf16x8 b1 = *(const bf16x8*)(lds + adr_qk(16 + q, 1024 + n * 128 + kk * 64 + g * 16));
            s[0][0] = mfma16(a0, b0, s[0][0]);
            s[0][1] = mfma16(a0, b1, s[0][1]);
            s[1][0] = mfma16(a1, b0, s[1][0]);
            s[1][1] = mfma16(a1, b1, s[1][1]);
        }
        float pv[2][2][4];
        #pragma unroll
        for (int it = 0; it < 2; ++it) {
            #pragma unroll
            for (int r = 0; r < 4; ++r) {
                float s0 = s[it][0][r] * 0.125f;
                float s1 = s[it][1][r] * 0.125f;
                float m = fmaxf(s0, s1);
                m = fmaxf(m, __shfl_xor(m, 1));
                m = fmaxf(m, __shfl_xor(m, 2));
                m = fmaxf(m, __shfl_xor(m, 4));
                m = fmaxf(m, __shfl_xor(m, 8));
                float p0 = __expf(s0 - m);
                float p1 = __expf(s1 - m);
                float ss = p0 + p1;
                ss += __shfl_xor(ss, 1);
                ss += __shfl_xor(ss, 2);
                ss += __shfl_xor(ss, 4);
                ss += __shfl_xor(ss, 8);
                float inv = 1.0f / ss;
                pv[it][0][r] = p0 * inv;
                pv[it][1][r] = p1 * inv;
            }
        }
        #pragma unroll
        for (int it = 0; it < 2; ++it)
            #pragma unroll
            for (int jt = 0; jt < 2; ++jt)
                #pragma unroll
                for (int r = 0; r < 4; ++r) {
                    const int i = it * 16 + 4 * g + r;
                    *(unsigned short*)(lds + adr_qk(i, n * 128 + (jt * 16 + q) * 2)) =
                        f2b(pv[it][jt][r]);
                }
        asm volatile("s_waitcnt lgkmcnt(0)" ::: "memory");
        __builtin_amdgcn_sched_barrier(0);
        bf16x8 pa0 = *(const bf16x8*)(lds + adr_qk(q,      n * 128 + g * 16));
        bf16x8 pa1 = *(const bf16x8*)(lds + adr_qk(16 + q, n * 128 + g * 16));
        #pragma unroll
        for (int et = 0; et < 4; ++et) {
            const int e = n * 64 + et * 16 + q;
            bf16x8 vb = *(const bf16x8*)(lds + adr_v(e, g * 16));
            f32x4 o0 = mfma16(pa0, vb, (f32x4)0.f);
            f32x4 o1 = mfma16(pa1, vb, (f32x4)0.f);
            const int cb = 1024 + n * 128 + (et * 16 + q) * 2;
            #pragma unroll
            for (int r = 0; r < 4; ++r) {
                *(unsigned short*)(lds + adr_qk(4 * g + r, cb))      = f2b(o0[r]);
                *(unsigned short*)(lds + adr_qk(16 + 4 * g + r, cb)) = f2b(o1[r]);
            }
        }
    }
    __syncthreads();
    for (int p4 = 0; p4 < 4; ++p4) {
        const int mt = wv * 4 + p4;
        f32x4 acc[2];
        acc[0] = (f32x4)0.f; acc[1] = (f32x4)0.f;
        #pragma unroll
        for (int kk = 0; kk < 16; ++kk) {
            bf16x8 b0 = *(const bf16x8*)(lds + adr_qk(q,      1024 + kk * 64 + g * 16));
            bf16x8 b1 = *(const bf16x8*)(lds + adr_qk(16 + q, 1024 + kk * 64 + g * 16));
            bf16x8 a  = *(const bf16x8*)((const char*)wo + (mt * 16 + q) * 1024 + kk * 64 + g * 16);
            acc[0] = mfma16(a, b0, acc[0]);
            acc[1] = mfma16(a, b1, acc[1]);
        }
        const int obase = mt * 16 + 4 * g;
        float bias[4];
        #pragma unroll
        for (int r = 0; r < 4; ++r) bias[r] = bo[obase + r];
        #pragma unroll
        for (int nt = 0; nt < 2; ++nt) {
            const int d = nt * 16 + q;
            uint2 xh = *(const uint2*)(lds + adr_x(d, obase * 2));
            uint2 xl = *(const uint2*)(lds + adr_xl(d, obase * 2));
            float res[4];
            res[0] = b2f(xh.x & 0xffffu) + b2f(xl.x & 0xffffu);
            res[1] = b2f(xh.x >> 16)     + b2f(xl.x >> 16);
            res[2] = b2f(xh.y & 0xffffu) + b2f(xl.y & 0xffffu);
            res[3] = b2f(xh.y >> 16)     + b2f(xl.y >> 16);
            #pragma unroll
            for (int r = 0; r < 4; ++r)
                ob[(obase + r) * 32768 + d * 1024] = acc[nt][r] + bias[r] + res[r];
        }
    }
}

// ======================= launch =======================
extern "C" void kernel_launch(void* const* d_in, const int* in_sizes, int n_in,
                              void* d_out, int out_size, void* d_ws, size_t ws_size,
                              hipStream_t stream) {
    const float* x     = (const float*)d_in[0];
    const float* w_qkv = (const float*)d_in[1];
    const float* b_qkv = (const float*)d_in[2];
    const float* w_out = (const float*)d_in[3];
    const float* b_out = (const float*)d_in[4];
    float* out = (float*)d_out;

    const size_t XB_OFF = 0;                 // 64 MB k-major tiles
    const size_t AO_OFF = 67108864;          // 64 MB bf16 [65536][512]
    const size_t WT_OFF = 134217728;         // 1.5 MB wT + 0.5 MB wo_bf
    const size_t NEED   = 136314880;

    if (ws_size >= NEED) {
        unsigned short* xB    = (unsigned short*)((char*)d_ws + XB_OFF);
        unsigned short* ao    = (unsigned short*)((char*)d_ws + AO_OFF);
        unsigned short* wTt   = (unsigned short*)((char*)d_ws + WT_OFF);
        unsigned short* wo_bf = wTt + 786432;
        xprep3   <<<dim3(2560), dim3(256), 0, stream>>>(x, w_qkv, w_out, xB, wTt, wo_bf);
        axial_ab4<<<dim3(2048), dim3(256), 0, stream>>>(xB, wTt, b_qkv, ao);
        axial_out<<<dim3(2048), dim3(256), 0, stream>>>(ao, wo_bf, b_out, x, out);
    } else {
        unsigned short* wbf = (unsigned short*)d_ws;
        wconvert<<<dim3(1024), dim3(256), 0, stream>>>(w_qkv, w_out, wbf);
        axial3d_mfma<<<dim3(2048), dim3(512), 0, stream>>>(x, b_qkv, b_out,
                                                           wbf, wbf + 786432, out);
    }
}